// Round 16
// baseline (765.203 us; speedup 1.0000x reference)
//
#include <hip/hip_runtime.h>

// AttentionHead: B=16384, W=10, D=1024, K=V=64
// out[b,i,:] = softmax_j( min(k_i . q_j, tri) ) @ v    (scores row = key index)
//
// GEMM front-end: 3-term split-FP16 MFMA. x = xh + xl*2^-11, w = wh + wl*2^-11
// (residuals pre-scaled by 2^11 -> fp16 normal range). f64-dot epilogue; f32 out.
//
// Round-16: PRODUCER-CONSUMER WAVE SPECIALIZATION. Wave 3 stages chunk t+1
// (load + fp16 split + ds_write) while waves 0-2 run MFMAs on chunk t —
// the convert phase no longer blocks the CU matrix pipe behind the barrier.
// Consumers each own 64 of the 192 output columns (acc[5][4]).
// One barrier per chunk; buffers disjoint (read t&1, write (t+1)&1).

#define D 1024
#define BM 80            // 8 batches of 10 rows per block
#define KCHUNKS 16       // 1024 / 64
#define ASTR 72          // staged row stride in shorts (64 data + 8 pad)
#define APIECE 11520     // bytes per staged piece [80][ASTR]
#define ABUF 23040       // bytes per staging buffer (2 pieces)
#define KQSTR 133        // kq row stride (floats)
#define VSTR 65          // v row stride (floats), overlay
#define SCOFF 42560      // byte offset of score buffer
#define SMEMSZ 46080     // 42560 + 4*220*4 == 2*ABUF
#define SCL 4.8828125e-4f   // 2^-11

typedef __attribute__((ext_vector_type(8))) _Float16 f16x8;
typedef __attribute__((ext_vector_type(4))) float f32x4;
typedef __attribute__((ext_vector_type(4))) unsigned short u16x4;

// --- kernel0: split wk|wq|wv into transposed fp16 2-piece Wt[n][k]
__global__ __launch_bounds__(256) void prep_w(const float* __restrict__ wk,
                                              const float* __restrict__ wq,
                                              const float* __restrict__ wv,
                                              unsigned short* __restrict__ wth,
                                              unsigned short* __restrict__ wtl) {
    int idx = blockIdx.x * 256 + threadIdx.x;   // idx = n*1024 + kk, n in [0,192)
    int n  = idx >> 10;
    int kk = idx & 1023;
    const float* src = (n < 64) ? wk : (n < 128) ? wq : wv;
    float w = src[kk * 64 + (n & 63)];
    _Float16 h = (_Float16)w;
    float r = (w - (float)h) * 2048.0f;         // pre-scaled residual
    _Float16 l = (_Float16)r;
    wth[idx] = __builtin_bit_cast(unsigned short, h);
    wtl[idx] = __builtin_bit_cast(unsigned short, l);
}

// producer: stage one 80x64 chunk (fp16 hi/lo) into buf; 4 batches of 5
// float4 per lane, 1-deep load pipeline (10 float4 live -> no spill).
static __device__ __forceinline__ void stage_chunk(
        const float* __restrict__ x, char* buf, int m0, int t, int lane) {
    unsigned short* H = (unsigned short*)buf;
    unsigned short* L = (unsigned short*)(buf + APIECE);
    const float* xc = x + (size_t)m0 * D + t * 64;
    float4 xa[5], xb[5];
    #pragma unroll
    for (int it = 0; it < 5; ++it) {
        int p = lane + it * 64;
        xa[it] = *reinterpret_cast<const float4*>(
            xc + (size_t)(p >> 4) * D + ((p & 15) << 2));
    }
    #pragma unroll
    for (int b = 0; b < 4; ++b) {
        if (b < 3) {
            #pragma unroll
            for (int it = 0; it < 5; ++it) {
                int p = lane + (b * 5 + 5 + it) * 64;
                xb[it] = *reinterpret_cast<const float4*>(
                    xc + (size_t)(p >> 4) * D + ((p & 15) << 2));
            }
        }
        #pragma unroll
        for (int it = 0; it < 5; ++it) {
            int p = lane + (b * 5 + it) * 64;
            int row = p >> 4;
            int c4  = (p & 15) << 2;
            float4 xv = xa[it];
            u16x4 hh, ll;
            #pragma unroll
            for (int e = 0; e < 4; ++e) {
                float xe = (e == 0) ? xv.x : (e == 1) ? xv.y : (e == 2) ? xv.z : xv.w;
                _Float16 h = (_Float16)xe;
                float rl = (xe - (float)h) * 2048.0f;
                _Float16 l = (_Float16)rl;
                hh[e] = __builtin_bit_cast(unsigned short, h);
                ll[e] = __builtin_bit_cast(unsigned short, l);
            }
            int ro = row * ASTR + c4;
            *reinterpret_cast<u16x4*>(H + ro) = hh;
            *reinterpret_cast<u16x4*>(L + ro) = ll;
        }
        if (b < 3) {
            #pragma unroll
            for (int it = 0; it < 5; ++it) xa[it] = xb[it];
        }
    }
}

// --- kernel1: fused 3-term fp16 projection GEMM + attention
__global__ __launch_bounds__(256, 3) void fused_attn(
        const float* __restrict__ x,
        const unsigned short* __restrict__ wth,
        const unsigned short* __restrict__ wtl,
        float* __restrict__ out) {

    __shared__ char smem[SMEMSZ];
    float* kq  = (float*)smem;                   // [80][KQSTR] = 42560 B
    float* vv  = (float*)smem;                   // [80][VSTR] overlay
    float* scw = (float*)(smem + SCOFF);         // [4][220] f32 probs

    const int tid  = threadIdx.x;
    const int wave = tid >> 6;            // 0..2 consumers, 3 producer
    const int lane = tid & 63;
    const int m0   = blockIdx.x * BM;
    const int arow  = lane & 15;
    const int apart = lane >> 4;          // 0..3
    const int nbase = wave * 64;          // consumer column base (4 n-tiles)

    // ---------- layout probe (register-only): acc (lane,reg) -> (row, col) ----
    f16x8 aprobe = {}, bone = {}, aone = {}, bcol = {};
    if (apart == 0) {
        aprobe[0] = (_Float16)(float)(arow + 1);  // A[m][0] = m+1
        bone[0]   = (_Float16)1.0f;               // B[0][n] = 1
        aone[0]   = (_Float16)1.0f;               // A[m][0] = 1
        bcol[0]   = (_Float16)(float)(arow + 1);  // B[0][n] = n+1
    }
    f32x4 z = {0.f, 0.f, 0.f, 0.f};
    f32x4 d1 = __builtin_amdgcn_mfma_f32_16x16x32_f16(aprobe, bone, z, 0, 0, 0); // row+1
    f32x4 d2 = __builtin_amdgcn_mfma_f32_16x16x32_f16(aone,  bcol, z, 0, 0, 0);  // col+1
    int R[4], Cc[4];
    #pragma unroll
    for (int r = 0; r < 4; ++r) {
        R[r]  = (int)(d1[r] + 0.5f) - 1;
        Cc[r] = (int)(d2[r] + 0.5f) - 1;
    }

    // ---------- GEMM: kqv[80][192] = x @ [wk|wq|wv], 3-term fp16 split -------
    f32x4 acc[5][4] = {};                 // 5 m-tiles x 4 n-tiles (consumers)

    if (wave == 3) stage_chunk(x, smem, m0, 0, lane);   // prologue: chunk 0
    __syncthreads();

    for (int t = 0; t < KCHUNKS; ++t) {
        if (wave < 3) {
            char* curb = smem + (t & 1) * ABUF;
            #pragma unroll
            for (int ks = 0; ks < 2; ++ks) {
                f16x8 wfh[4], wfl[4];
                #pragma unroll
                for (int nt = 0; nt < 4; ++nt) {
                    int n = nbase + nt * 16 + arow;
                    size_t off = (size_t)n * D + t * 64 + ks * 32 + apart * 8;
                    wfh[nt] = *reinterpret_cast<const f16x8*>(wth + off);
                    wfl[nt] = *reinterpret_cast<const f16x8*>(wtl + off);
                }
                #pragma unroll
                for (int mt = 0; mt < 5; ++mt) {
                    int ab = (mt * 16 + arow) * (ASTR * 2) + (ks * 4 + apart) * 16;
                    f16x8 ah = *reinterpret_cast<const f16x8*>(curb + ab);
                    f16x8 al = *reinterpret_cast<const f16x8*>(curb + APIECE + ab);
                    #pragma unroll
                    for (int nt = 0; nt < 4; ++nt) {
                        acc[mt][nt] = __builtin_amdgcn_mfma_f32_16x16x32_f16(ah, wfh[nt], acc[mt][nt], 0, 0, 0);
                        f32x4 tt = {0.f, 0.f, 0.f, 0.f};
                        tt = __builtin_amdgcn_mfma_f32_16x16x32_f16(ah, wfl[nt], tt, 0, 0, 0);
                        tt = __builtin_amdgcn_mfma_f32_16x16x32_f16(al, wfh[nt], tt, 0, 0, 0);
                        #pragma unroll
                        for (int c = 0; c < 4; ++c)
                            acc[mt][nt][c] = fmaf(tt[c], SCL, acc[mt][nt][c]);
                    }
                }
            }
        } else {
            if (t < KCHUNKS - 1)
                stage_chunk(x, smem + ((t + 1) & 1) * ABUF, m0, t + 1, lane);
        }
        __syncthreads();   // chunk t consumed; chunk t+1 staged
    }

    // ---------- epilogue: two-phase (kq -> scores -> v overlay -> PV) ----------
    // phase 1: consumers dump k,q columns (col < 128)
    if (wave < 3) {
        #pragma unroll
        for (int mt = 0; mt < 5; ++mt) {
            #pragma unroll
            for (int r = 0; r < 4; ++r) {
                int row = mt * 16 + R[r];
                #pragma unroll
                for (int nt = 0; nt < 4; ++nt) {
                    int colbase = nbase + nt * 16;
                    if (colbase < 128)
                        kq[row * KQSTR + colbase + Cc[r]] = acc[mt][nt][r];
                }
            }
        }
    }
    __syncthreads();

    // phase 2: masked scores for both batches of this wave (f64 dots, f32 store)
    float* sc0 = scw + wave * 220;
    #pragma unroll
    for (int bb = 0; bb < 2; ++bb) {
        const int r0 = (wave * 2 + bb) * 10;
        float* sc = sc0 + bb * 110;
        #pragma unroll
        for (int it = 0; it < 2; ++it) {
            int p = it * 64 + lane;
            if (p < 100) {
                int i = p / 10;
                int j = p - i * 10;
                double s = 0.0;
                #pragma unroll 8
                for (int c = 0; c < 64; ++c)
                    s += (double)kq[(r0 + i) * KQSTR + c] *
                         (double)kq[(r0 + j) * KQSTR + 64 + c];
                double lim = (j <= i) ? 1e5 : -1e5;
                sc[i * 11 + j] = (float)fmin(s, lim);
            }
        }
    }
    __syncthreads();   // kq reads done -> safe to overlay v

    // phase 3: softmax (lanes 0-9, f64 from f32 scores) + v dump (cols >= 128)
    if (lane < 10) {
        int i = lane;
        #pragma unroll
        for (int bb = 0; bb < 2; ++bb) {
            float* sc = sc0 + bb * 110;
            double vals[10];
            double mx = -1e300;
            #pragma unroll
            for (int j = 0; j < 10; ++j) { vals[j] = (double)sc[i * 11 + j]; mx = fmax(mx, vals[j]); }
            double sum = 0.0;
            #pragma unroll
            for (int j = 0; j < 10; ++j) { vals[j] = exp(vals[j] - mx); sum += vals[j]; }
            double inv = 1.0 / sum;
            #pragma unroll
            for (int j = 0; j < 10; ++j) sc[i * 11 + j] = (float)(vals[j] * inv);
        }
    }
    if (wave < 3) {
        #pragma unroll
        for (int mt = 0; mt < 5; ++mt) {
            #pragma unroll
            for (int r = 0; r < 4; ++r) {
                int row = mt * 16 + R[r];
                #pragma unroll
                for (int nt = 0; nt < 4; ++nt) {
                    int colbase = nbase + nt * 16;
                    if (colbase >= 128)
                        vv[row * VSTR + (colbase - 128) + Cc[r]] = acc[mt][nt][r];
                }
            }
        }
    }
    __syncthreads();

    // phase 4: PV (f64 accum, f32 probs/v) + f32 store; lane = output column
    #pragma unroll
    for (int bb = 0; bb < 2; ++bb) {
        const int bloc = wave * 2 + bb;
        const int r0   = bloc * 10;
        float* sc = sc0 + bb * 110;
        size_t ob = (size_t)(blockIdx.x * 8 + bloc) * 640;
        #pragma unroll
        for (int i = 0; i < 10; ++i) {
            double o = 0.0;
            #pragma unroll
            for (int j = 0; j < 10; ++j)
                o += (double)sc[i * 11 + j] * (double)vv[(r0 + j) * VSTR + lane];
            out[ob + (size_t)i * 64 + lane] = (float)o;
        }
    }
}

extern "C" void kernel_launch(void* const* d_in, const int* in_sizes, int n_in,
                              void* d_out, int out_size, void* d_ws, size_t ws_size,
                              hipStream_t stream) {
    const float* x  = (const float*)d_in[0];
    const float* wk = (const float*)d_in[1];
    const float* wq = (const float*)d_in[2];
    const float* wv = (const float*)d_in[3];
    unsigned short* wth = (unsigned short*)d_ws;          // 2 x 192*1024 fp16
    unsigned short* wtl = wth + 192 * 1024;
    float* outp = (float*)d_out;                          // FLOAT32 output

    prep_w<<<768, 256, 0, stream>>>(wk, wq, wv, wth, wtl);
    fused_attn<<<2048, 256, 0, stream>>>(x, wth, wtl, outp);
}

// Round 17
// 364.716 us; speedup vs baseline: 2.0981x; 2.0981x over previous
//
#include <hip/hip_runtime.h>

// AttentionHead: B=16384, W=10, D=1024, K=V=64
// out[b,i,:] = softmax_j( min(k_i . q_j, tri) ) @ v    (scores row = key index)
//
// GEMM front-end: 3-term split-FP16 MFMA. x = xh + xl*2^-11, w = wh + wl*2^-11
// (residuals pre-scaled by 2^11 -> fp16 normal range). f64-dot epilogue; f32 out.
//
// Round-17: BALANCED producer-consumer wave specialization (R16 postmortem:
// 1 producer couldn't keep up + MFMA missing from SIMD 3). 8 waves:
//   waves 0-3 = consumers, one per SIMD (R14's exact per-wave MFMA load)
//   waves 4-7 = producers, one per SIMD (R14's exact per-wave staging share)
// Staging of chunk t+1 runs CONCURRENTLY with MFMAs on chunk t in separate
// waves on the same SIMD -> the convert phase leaves the matrix-pipe path.
// One barrier/chunk; disjoint buffers; setprio(1) on the MFMA cluster (T5 --
// true role diversity now exists). launch_bounds(512,4): VGPR cap 128.

#define D 1024
#define BM 80            // 8 batches of 10 rows per block
#define KCHUNKS 16       // 1024 / 64
#define ASTR 72          // staged row stride in shorts (64 data + 8 pad)
#define APIECE 11520     // bytes per staged piece [80][ASTR]
#define ABUF 23040       // bytes per staging buffer (2 pieces)
#define KQSTR 133        // kq row stride (floats)
#define VSTR 65          // v row stride (floats), overlay
#define SCOFF 42560      // byte offset of score buffer
#define SMEMSZ 46080     // 42560 + 8*110*4 == 2*ABUF
#define SCL 4.8828125e-4f   // 2^-11

typedef __attribute__((ext_vector_type(8))) _Float16 f16x8;
typedef __attribute__((ext_vector_type(4))) float f32x4;
typedef __attribute__((ext_vector_type(4))) unsigned short u16x4;

// --- kernel0: split wk|wq|wv into transposed fp16 2-piece Wt[n][k]
__global__ __launch_bounds__(256) void prep_w(const float* __restrict__ wk,
                                              const float* __restrict__ wq,
                                              const float* __restrict__ wv,
                                              unsigned short* __restrict__ wth,
                                              unsigned short* __restrict__ wtl) {
    int idx = blockIdx.x * 256 + threadIdx.x;   // idx = n*1024 + kk, n in [0,192)
    int n  = idx >> 10;
    int kk = idx & 1023;
    const float* src = (n < 64) ? wk : (n < 128) ? wq : wv;
    float w = src[kk * 64 + (n & 63)];
    _Float16 h = (_Float16)w;
    float r = (w - (float)h) * 2048.0f;         // pre-scaled residual
    _Float16 l = (_Float16)r;
    wth[idx] = __builtin_bit_cast(unsigned short, h);
    wtl[idx] = __builtin_bit_cast(unsigned short, l);
}

// --- kernel1: fused 3-term fp16 projection GEMM + attention
__global__ __launch_bounds__(512, 4) void fused_attn(
        const float* __restrict__ x,
        const unsigned short* __restrict__ wth,
        const unsigned short* __restrict__ wtl,
        float* __restrict__ out) {

    __shared__ char smem[SMEMSZ];
    float* kq  = (float*)smem;                   // [80][KQSTR] = 42560 B
    float* vv  = (float*)smem;                   // [80][VSTR] overlay
    float* scw = (float*)(smem + SCOFF);         // [8][110] f32 probs

    const int tid  = threadIdx.x;
    const int wave = tid >> 6;            // 0-3 consumers, 4-7 producers
    const int lane = tid & 63;
    const int m0   = blockIdx.x * BM;
    const int arow  = lane & 15;
    const int apart = lane >> 4;          // 0..3
    const bool consumer = (wave < 4);
    const int nbase = wave * 48;          // consumer column base (3 n-tiles)

    // ---------- layout probe (register-only): acc (lane,reg) -> (row, col) ----
    f16x8 aprobe = {}, bone = {}, aone = {}, bcol = {};
    if (apart == 0) {
        aprobe[0] = (_Float16)(float)(arow + 1);  // A[m][0] = m+1
        bone[0]   = (_Float16)1.0f;               // B[0][n] = 1
        aone[0]   = (_Float16)1.0f;               // A[m][0] = 1
        bcol[0]   = (_Float16)(float)(arow + 1);  // B[0][n] = n+1
    }
    f32x4 z = {0.f, 0.f, 0.f, 0.f};
    f32x4 d1 = __builtin_amdgcn_mfma_f32_16x16x32_f16(aprobe, bone, z, 0, 0, 0); // row+1
    f32x4 d2 = __builtin_amdgcn_mfma_f32_16x16x32_f16(aone,  bcol, z, 0, 0, 0);  // col+1
    int R[4], Cc[4];
    #pragma unroll
    for (int r = 0; r < 4; ++r) {
        R[r]  = (int)(d1[r] + 0.5f) - 1;
        Cc[r] = (int)(d2[r] + 0.5f) - 1;
    }

    // producer staging coords: s in [0,256) over the 4 producer waves
    int srow[5], scol[5];
    {
        int s = ((wave & 3) << 6) | lane;
        #pragma unroll
        for (int it = 0; it < 5; ++it) {
            int p = s + it * 256;
            srow[it] = p >> 4;
            scol[it] = (p & 15) << 2;
        }
    }

    // ---------- GEMM: kqv[80][192] = x @ [wk|wq|wv], 3-term fp16 split -------
    f32x4 acc[5][3] = {};                 // consumers: 5 m-tiles x 3 n-tiles

    // prologue: producers stage chunk 0 into buffer 0
    if (!consumer) {
        unsigned short* H = (unsigned short*)smem;
        unsigned short* L = (unsigned short*)(smem + APIECE);
        float4 xv[5];
        #pragma unroll
        for (int it = 0; it < 5; ++it)
            xv[it] = *reinterpret_cast<const float4*>(
                x + (size_t)(m0 + srow[it]) * D + scol[it]);
        #pragma unroll
        for (int it = 0; it < 5; ++it) {
            u16x4 hh, ll;
            #pragma unroll
            for (int e = 0; e < 4; ++e) {
                float xe = (e == 0) ? xv[it].x : (e == 1) ? xv[it].y : (e == 2) ? xv[it].z : xv[it].w;
                _Float16 h = (_Float16)xe;
                float rl = (xe - (float)h) * 2048.0f;
                _Float16 l = (_Float16)rl;
                hh[e] = __builtin_bit_cast(unsigned short, h);
                ll[e] = __builtin_bit_cast(unsigned short, l);
            }
            int ro = srow[it] * ASTR + scol[it];
            *reinterpret_cast<u16x4*>(H + ro) = hh;
            *reinterpret_cast<u16x4*>(L + ro) = ll;
        }
    }
    __syncthreads();

    for (int t = 0; t < KCHUNKS; ++t) {
        if (consumer) {
            char* curb = smem + (t & 1) * ABUF;
            __builtin_amdgcn_s_setprio(1);
            #pragma unroll
            for (int ks = 0; ks < 2; ++ks) {
                f16x8 wfh[3], wfl[3];
                #pragma unroll
                for (int nt = 0; nt < 3; ++nt) {
                    int n = nbase + nt * 16 + arow;
                    size_t off = (size_t)n * D + t * 64 + ks * 32 + apart * 8;
                    wfh[nt] = *reinterpret_cast<const f16x8*>(wth + off);
                    wfl[nt] = *reinterpret_cast<const f16x8*>(wtl + off);
                }
                #pragma unroll
                for (int mt = 0; mt < 5; ++mt) {
                    int ab = (mt * 16 + arow) * (ASTR * 2) + (ks * 4 + apart) * 16;
                    f16x8 ah = *reinterpret_cast<const f16x8*>(curb + ab);
                    f16x8 al = *reinterpret_cast<const f16x8*>(curb + APIECE + ab);
                    #pragma unroll
                    for (int nt = 0; nt < 3; ++nt) {
                        acc[mt][nt] = __builtin_amdgcn_mfma_f32_16x16x32_f16(ah, wfh[nt], acc[mt][nt], 0, 0, 0);
                        f32x4 tt = {0.f, 0.f, 0.f, 0.f};
                        tt = __builtin_amdgcn_mfma_f32_16x16x32_f16(ah, wfl[nt], tt, 0, 0, 0);
                        tt = __builtin_amdgcn_mfma_f32_16x16x32_f16(al, wfh[nt], tt, 0, 0, 0);
                        #pragma unroll
                        for (int c = 0; c < 4; ++c)
                            acc[mt][nt][c] = fmaf(tt[c], SCL, acc[mt][nt][c]);
                    }
                }
            }
            __builtin_amdgcn_s_setprio(0);
        } else if (t < KCHUNKS - 1) {
            // producers: stage chunk t+1 into the other buffer (concurrent
            // with consumer MFMAs on this SIMD)
            char* nxtb = smem + ((t + 1) & 1) * ABUF;
            unsigned short* H = (unsigned short*)nxtb;
            unsigned short* L = (unsigned short*)(nxtb + APIECE);
            float4 xv[5];
            #pragma unroll
            for (int it = 0; it < 5; ++it)
                xv[it] = *reinterpret_cast<const float4*>(
                    x + (size_t)(m0 + srow[it]) * D + (t + 1) * 64 + scol[it]);
            #pragma unroll
            for (int it = 0; it < 5; ++it) {
                u16x4 hh, ll;
                #pragma unroll
                for (int e = 0; e < 4; ++e) {
                    float xe = (e == 0) ? xv[it].x : (e == 1) ? xv[it].y : (e == 2) ? xv[it].z : xv[it].w;
                    _Float16 h = (_Float16)xe;
                    float rl = (xe - (float)h) * 2048.0f;
                    _Float16 l = (_Float16)rl;
                    hh[e] = __builtin_bit_cast(unsigned short, h);
                    ll[e] = __builtin_bit_cast(unsigned short, l);
                }
                int ro = srow[it] * ASTR + scol[it];
                *reinterpret_cast<u16x4*>(H + ro) = hh;
                *reinterpret_cast<u16x4*>(L + ro) = ll;
            }
        }
        __syncthreads();   // chunk t consumed; chunk t+1 staged
    }

    // ---------- epilogue: two-phase (kq -> scores -> v overlay -> PV) ----------
    // phase 1: consumers dump k,q columns (col < 128)
    if (consumer) {
        #pragma unroll
        for (int mt = 0; mt < 5; ++mt) {
            #pragma unroll
            for (int r = 0; r < 4; ++r) {
                int row = mt * 16 + R[r];
                #pragma unroll
                for (int nt = 0; nt < 3; ++nt) {
                    int colbase = nbase + nt * 16;
                    if (colbase < 128)
                        kq[row * KQSTR + colbase + Cc[r]] = acc[mt][nt][r];
                }
            }
        }
    }
    __syncthreads();

    // phase 2: masked scores; each wave owns batch `wave` (f64 dots, f32 store)
    const int r0 = wave * 10;
    float* sc = scw + wave * 110;
    #pragma unroll
    for (int it = 0; it < 2; ++it) {
        int p = it * 64 + lane;
        if (p < 100) {
            int i = p / 10;
            int j = p - i * 10;
            double s = 0.0;
            #pragma unroll 8
            for (int c = 0; c < 64; ++c)
                s += (double)kq[(r0 + i) * KQSTR + c] *
                     (double)kq[(r0 + j) * KQSTR + 64 + c];
            double lim = (j <= i) ? 1e5 : -1e5;
            sc[i * 11 + j] = (float)fmin(s, lim);
        }
    }
    __syncthreads();   // kq reads done -> safe to overlay v

    // phase 3: softmax (lanes 0-9, own batch) + consumer v dump (cols >= 128)
    if (lane < 10) {
        int i = lane;
        double vals[10];
        double mx = -1e300;
        #pragma unroll
        for (int j = 0; j < 10; ++j) { vals[j] = (double)sc[i * 11 + j]; mx = fmax(mx, vals[j]); }
        double sum = 0.0;
        #pragma unroll
        for (int j = 0; j < 10; ++j) { vals[j] = exp(vals[j] - mx); sum += vals[j]; }
        double inv = 1.0 / sum;
        #pragma unroll
        for (int j = 0; j < 10; ++j) sc[i * 11 + j] = (float)(vals[j] * inv);
    }
    if (consumer) {
        #pragma unroll
        for (int mt = 0; mt < 5; ++mt) {
            #pragma unroll
            for (int r = 0; r < 4; ++r) {
                int row = mt * 16 + R[r];
                #pragma unroll
                for (int nt = 0; nt < 3; ++nt) {
                    int colbase = nbase + nt * 16;
                    if (colbase >= 128)
                        vv[row * VSTR + (colbase - 128) + Cc[r]] = acc[mt][nt][r];
                }
            }
        }
    }
    __syncthreads();

    // phase 4: PV (f64 accum, f32 probs/v) + f32 store; lane = output column
    {
        size_t ob = (size_t)(blockIdx.x * 8 + wave) * 640;
        #pragma unroll
        for (int i = 0; i < 10; ++i) {
            double o = 0.0;
            #pragma unroll
            for (int j = 0; j < 10; ++j)
                o += (double)sc[i * 11 + j] * (double)vv[(r0 + j) * VSTR + lane];
            out[ob + (size_t)i * 64 + lane] = (float)o;
        }
    }
}

extern "C" void kernel_launch(void* const* d_in, const int* in_sizes, int n_in,
                              void* d_out, int out_size, void* d_ws, size_t ws_size,
                              hipStream_t stream) {
    const float* x  = (const float*)d_in[0];
    const float* wk = (const float*)d_in[1];
    const float* wq = (const float*)d_in[2];
    const float* wv = (const float*)d_in[3];
    unsigned short* wth = (unsigned short*)d_ws;          // 2 x 192*1024 fp16
    unsigned short* wtl = wth + 192 * 1024;
    float* outp = (float*)d_out;                          // FLOAT32 output

    prep_w<<<768, 256, 0, stream>>>(wk, wq, wv, wth, wtl);
    fused_attn<<<2048, 512, 0, stream>>>(x, wth, wtl, outp);
}